// Round 2
// baseline (234.615 us; speedup 1.0000x reference)
//
#include <hip/hip_runtime.h>

// LatticeCrf log_prob on MI355X — MFMA chunked linear-space scan.
// P_c = M_c^T tracked via P <- E_t^T * P, two v_mfma_f32_32x32x16_bf16 per step.
// Contraction-index permutation sigma folded into A-operand load offsets so the
// fp32 accumulator (C-layout) feeds the B operand directly after bf16 packing.
#define BB 64
#define TT 512
#define VV 32
#define LOG2E 1.4426950408889634f
#define LN2f  0.6931471805599453f
#define SHIFT 6.0f

typedef __bf16 bf16x8 __attribute__((ext_vector_type(8)));
typedef float  f32x16 __attribute__((ext_vector_type(16)));

union Frag { unsigned int u[4]; bf16x8 v; };

// round-half-up fp32->bf16, pack two into one dword via v_perm_b32
__device__ __forceinline__ unsigned int pack_bf16(float lo, float hi) {
    unsigned int a = __float_as_uint(lo) + 0x8000u;
    unsigned int b = __float_as_uint(hi) + 0x8000u;
    // dst = [a.b2, a.b3, b.b2, b.b3] : sel indices 2,3 from low operand, 6,7 from high
    return __builtin_amdgcn_perm(b, a, 0x07060302u);
}

__global__ __launch_bounds__(256) void crf_chunk_kernel(
    const float* __restrict__ scores,
    const float* __restrict__ w_tx,
    const float* __restrict__ w_dur,
    float* __restrict__ ws_M,
    int CC, int L)
{
    const int lane = threadIdx.x & 63;
    const int wid  = threadIdx.x >> 6;
    const int chunk = blockIdx.x * 4 + wid;
    const int m = lane & 31;           // output column of P (row of M)
    const int h = lane >> 5;

    // sigma(j,h) = (j&3) + 8*(j>>2) + 4h  (row of E this A-slot carries)
    // float offset within a 1024-elem step matrix: sigma*32 + m
    const int base = h * 128 + m;

    // preload w2[j] = (w_tx+w_dur)[sigma][m]*log2e - SHIFT
    float w2[16];
#pragma unroll
    for (int j = 0; j < 8; ++j) {
        const int off = base + (j & 3) * 32 + (j >> 2) * 256;
        w2[j]     = (w_tx[off]       + w_dur[off])       * LOG2E - SHIFT;
        w2[j + 8] = (w_tx[off + 512] + w_dur[off + 512]) * LOG2E - SHIFT;
    }

    const int b = chunk / CC, c = chunk - b * CC;
    const float* sc = scores + ((size_t)(b * TT + c * L)) * 1024 + base;

    // preload step 0
    float s[16];
#pragma unroll
    for (int j = 0; j < 8; ++j) {
        const int off = (j & 3) * 32 + (j >> 2) * 256;
        s[j]     = sc[off];
        s[j + 8] = sc[off + 512];
    }

    // acc = P in C-layout, init identity: reg r holds P[mr][m], mr=(r&3)+8*(r>>2)+4h
    f32x16 acc;
#pragma unroll
    for (int r = 0; r < 16; ++r) {
        const int mr = (r & 3) + 8 * (r >> 2) + 4 * h;
        acc[r] = (mr == m) ? 1.0f : 0.0f;
    }

    for (int t = 0; t < L; ++t) {
        float fa[16];
#pragma unroll
        for (int j = 0; j < 16; ++j) fa[j] = __builtin_fmaf(s[j], LOG2E, w2[j]);

        // prefetch next step while computing this one
        if (t + 1 < L) {
            const float* sn = sc + (size_t)(t + 1) * 1024;
#pragma unroll
            for (int j = 0; j < 8; ++j) {
                const int off = (j & 3) * 32 + (j >> 2) * 256;
                s[j]     = sn[off];
                s[j + 8] = sn[off + 512];
            }
        }

        float e[16];
#pragma unroll
        for (int j = 0; j < 16; ++j) e[j] = __builtin_amdgcn_exp2f(fa[j]);

        Frag a1, a2, b1, b2;
#pragma unroll
        for (int p = 0; p < 4; ++p) {
            a1.u[p] = pack_bf16(e[2 * p],        e[2 * p + 1]);
            a2.u[p] = pack_bf16(e[8 + 2 * p],    e[8 + 2 * p + 1]);
            b1.u[p] = pack_bf16(acc[2 * p],      acc[2 * p + 1]);
            b2.u[p] = pack_bf16(acc[8 + 2 * p],  acc[8 + 2 * p + 1]);
        }

        f32x16 z;
#pragma unroll
        for (int r = 0; r < 16; ++r) z[r] = 0.0f;
        f32x16 tmp = __builtin_amdgcn_mfma_f32_32x32x16_bf16(a1.v, b1.v, z,   0, 0, 0);
        acc        = __builtin_amdgcn_mfma_f32_32x32x16_bf16(a2.v, b2.v, tmp, 0, 0, 0);
    }

    // write P row-major: P[mr][m] -> ws[chunk*1024 + mr*32 + m]
    float* outP = ws_M + (size_t)chunk * 1024;
#pragma unroll
    for (int r = 0; r < 16; ++r) {
        const int mr = (r & 3) + 8 * (r >> 2) + 4 * h;
        outP[mr * 32 + m] = acc[r];
    }
}

__global__ __launch_bounds__(64) void crf_combine_kernel(
    const float* __restrict__ scores,
    const int*   __restrict__ targets,
    const float* __restrict__ w_tx,
    const float* __restrict__ w_init,
    const float* __restrict__ w_final,
    const float* __restrict__ w_dur,
    const float* __restrict__ ws_M,
    float* __restrict__ out,
    int CC)
{
    const int b    = blockIdx.x;
    const int lane = threadIdx.x;   // 0..63

    // ---- numerator ----
    const int* tg = targets + b * (TT + 1);
    float num = 0.f;
#pragma unroll
    for (int k = 0; k < TT / 64; ++k) {
        const int t  = lane + 64 * k;
        const int s_ = tg[t];
        const int d_ = tg[t + 1];
        const int wi = s_ * VV + d_;
        num += scores[(((size_t)b * TT + t) * VV + s_) * VV + d_] + w_tx[wi] + w_dur[wi];
    }
#pragma unroll
    for (int mS = 32; mS >= 1; mS >>= 1) num += __shfl_xor(num, mS, 64);

    // ---- denominator: a <- a * M_c, i.e. a_new[j] = dot(P_c row j, a) ----
    const int j = lane & 31;
    float a    = __builtin_amdgcn_exp2f(w_init[j] * LOG2E);
    float accl = 0.f;
    const float* Pb = ws_M + (size_t)b * CC * 1024;

    float4 rr[8];
#pragma unroll
    for (int q = 0; q < 8; ++q) rr[q] = *(const float4*)(Pb + j * 32 + 4 * q);

    for (int c = 0; c < CC; ++c) {
        float4 rn[8];
        if (c + 1 < CC) {
            const float* Pn = Pb + (size_t)(c + 1) * 1024 + j * 32;
#pragma unroll
            for (int q = 0; q < 8; ++q) rn[q] = *(const float4*)(Pn + 4 * q);
        }
        float an = 0.f;
#pragma unroll
        for (int i = 0; i < 32; ++i) {
            const float  ai = __shfl(a, i, 32);
            const float4 v  = rr[i >> 2];
            const float  pv = ((i & 3) == 0) ? v.x : ((i & 3) == 1) ? v.y
                             : ((i & 3) == 2) ? v.z : v.w;
            an = __builtin_fmaf(ai, pv, an);
        }
        float mx = an;
#pragma unroll
        for (int mS = 16; mS >= 1; mS >>= 1) mx = fmaxf(mx, __shfl_xor(mx, mS, 32));
        a = an / mx;
        accl += __builtin_amdgcn_logf(mx);   // log2
        if (c + 1 < CC) {
#pragma unroll
            for (int q = 0; q < 8; ++q) rr[q] = rn[q];
        }
    }

    float rf = a * __builtin_amdgcn_exp2f(w_final[j] * LOG2E);
    float ss = rf;
#pragma unroll
    for (int mS = 16; mS >= 1; mS >>= 1) ss += __shfl_xor(ss, mS, 32);
    const float denom_ln =
        (__builtin_amdgcn_logf(ss) + accl + SHIFT * (float)TT) * LN2f;

    if (lane == 0) {
        out[b] = num + w_init[tg[0]] + w_final[tg[TT]] - denom_ln;
    }
}

extern "C" void kernel_launch(void* const* d_in, const int* in_sizes, int n_in,
                              void* d_out, int out_size, void* d_ws, size_t ws_size,
                              hipStream_t stream) {
    const float* scores  = (const float*)d_in[0];
    const int*   targets = (const int*)d_in[1];
    const float* w_tx    = (const float*)d_in[2];
    const float* w_init  = (const float*)d_in[3];
    const float* w_final = (const float*)d_in[4];
    const float* w_dur   = (const float*)d_in[5];
    float*       out     = (float*)d_out;
    float*       ws_M    = (float*)d_ws;

    int CC = 8;   // needs BB*CC*4KB of workspace
    if      (ws_size >= (size_t)BB * 32 * 4096) CC = 32;
    else if (ws_size >= (size_t)BB * 16 * 4096) CC = 16;
    const int L = TT / CC;

    crf_chunk_kernel<<<BB * CC / 4, 256, 0, stream>>>(scores, w_tx, w_dur, ws_M, CC, L);
    crf_combine_kernel<<<BB, 64, 0, stream>>>(scores, targets, w_tx, w_init,
                                              w_final, w_dur, ws_M, out, CC);
}